// Round 13
// baseline (341.674 us; speedup 1.0000x reference)
//
#include <hip/hip_runtime.h>
#include <hip/hip_bf16.h>

// NonLocalBlock: B=8, C=512, CI=256, H=W=56, N=3136.
// Round-22: bn_apply reads the residual from xT (bf16, [b][N][C], same
// layout as wy -> same coalesced tile pass) instead of re-reading x
// (103 MB fp32). Saves 52 MB of HBM reads. fl=1: xT==x bit-identical;
// fl=0: residual bf16 rounding <= ~0.011 abs vs 0.076 margin.
// Everything else frozen: attn R19 (XCD-grouped, z-split 2), gemm_proj
// R20 (BK=64, XCD-grouped), gemm_w R21 (n-paired 128x256, XCD-grouped).
// Dispatches (6): convert_params, transpose_x, gemm_proj, attn, gemm_w,
// bn_apply.

typedef unsigned short u16;
typedef unsigned int u32;
typedef __attribute__((ext_vector_type(8))) short short8;   // 8 bf16
typedef __attribute__((ext_vector_type(4))) float floatx4;
typedef __attribute__((ext_vector_type(4))) u32 uint4v;

#define B_   8
#define C_   512
#define CI_  256
#define N_   3136
#define BN_  25088   // B_*N_

__device__ __forceinline__ u16 f2b(float f) {
    return __builtin_bit_cast(u16, __float2bfloat16(f));
}
__device__ __forceinline__ float b2f(u16 u) {
    return __bfloat162float(__builtin_bit_cast(__hip_bfloat16, u));
}
__device__ __forceinline__ floatx4 mfma16(short8 a, short8 b, floatx4 c) {
    return __builtin_amdgcn_mfma_f32_16x16x32_bf16(a, b, c, 0, 0, 0);
}
// async global->LDS DMA, 16 B/lane; LDS dest = wave-uniform base + lane*16,
// source address fully per-lane (gather).
__device__ __forceinline__ void gload_lds16(const u16* g, u16* l) {
    __builtin_amdgcn_global_load_lds(
        (const __attribute__((address_space(1))) u32*)g,
        (__attribute__((address_space(3))) u32*)l, 16, 0, 0);
}

// Per-block dtype flag from a 4KB x prefix (bf16-pair vs fp32 mantissa noise).
// Call at kernel top with all 256 threads active.
__device__ __forceinline__ int block_flag(const void* x) {
    __shared__ int cnt_;
    if (threadIdx.x == 0) cnt_ = 0;
    __syncthreads();
    const u32* xw = (const u32*)x;
    int c = 0;
#pragma unroll
    for (int i = 0; i < 4; ++i) {
        u32 w = xw[threadIdx.x * 4 + i];
        u32 e = (w >> 7) & 0xFF;
        c += (e >= 118 && e <= 130) ? 1 : 0;
    }
    atomicAdd(&cnt_, c);
    __syncthreads();
    return (2 * cnt_ > 1024) ? 1 : 0;
}

// ---------------------------------------------------------------------------
// Convert 10 parameter arrays into canonical bf16 (flag inline).
// Block (0,0) additionally zeroes the BN stats buffer.
// ---------------------------------------------------------------------------
__global__ __launch_bounds__(256) void convert_params(
    const void* __restrict__ x,
    const void* tw, const void* tb, const void* pw, const void* pb,
    const void* gw, const void* gbi, const void* ww, const void* wb,
    const void* gamma, const void* beta,
    u16* __restrict__ dst, float* __restrict__ stats)
{
    const int fl = block_flag(x);
    if (blockIdx.x == 0 && blockIdx.y == 0) {
        stats[threadIdx.x] = 0.f;
        stats[threadIdx.x + 256] = 0.f;
        stats[threadIdx.x + 512] = 0.f;
        stats[threadIdx.x + 768] = 0.f;
    }
    const void* srcs[10] = {tw, tb, pw, pb, gw, gbi, ww, wb, gamma, beta};
    const int ns[10] = {131072, 256, 131072, 256, 131072, 256, 131072, 512, 512, 512};
    int seg = blockIdx.y;
    int off = 0;
    for (int s = 0; s < 10; ++s) { if (s == seg) break; off += ns[s]; }
    const void* src = srcs[seg];
    int n = ns[seg];
    int i0 = (blockIdx.x * 256 + threadIdx.x) * 8;
    if (i0 >= n) return;
    u16* d = dst + off;
    for (int k = 0; k < 8; ++k) {
        int i = i0 + k;
        if (i < n)
            d[i] = fl ? ((const u16*)src)[i] : f2b(((const float*)src)[i]);
    }
}

// ---------------------------------------------------------------------------
// x ingest + transpose: x [b,C,N] (fp32 or bf16) -> xT [b,N,C] bf16.
// ---------------------------------------------------------------------------
__global__ __launch_bounds__(256) void transpose_x(
    const void* __restrict__ in, u16* __restrict__ out)
{
    const int fl = block_flag(in);
    __shared__ u16 tile[64][68];
    const int t = threadIdx.x;
    const long base = (long)blockIdx.z * (long)C_ * (long)N_;
    const int c0 = blockIdx.x * 64, r0 = blockIdx.y * 64;
    const int lr = t >> 3;
    const int lc = (t & 7) * 8;
#pragma unroll
    for (int j = 0; j < 2; ++j) {
        int rr = lr + 32 * j;
        long eoff = base + (long)(r0 + rr) * N_ + c0 + lc;
        u16 v[8] __attribute__((aligned(16)));
        if (fl) {
            const u16* pi = (const u16*)in + eoff;
            *(uint64_t*)&v[0] = *(const uint64_t*)pi;
            *(uint64_t*)&v[4] = *(const uint64_t*)(pi + 4);
        } else {
            const float* pi = (const float*)in + eoff;
            floatx4 a = *(const floatx4*)pi;
            floatx4 b4 = *(const floatx4*)(pi + 4);
#pragma unroll
            for (int k = 0; k < 4; ++k) { v[k] = f2b(a[k]); v[4 + k] = f2b(b4[k]); }
        }
        *(uint64_t*)&tile[rr][lc] = *(const uint64_t*)&v[0];
        *(uint64_t*)&tile[rr][lc + 4] = *(const uint64_t*)&v[4];
    }
    __syncthreads();
#pragma unroll
    for (int j = 0; j < 2; ++j) {
        int oc = lr + 32 * j;
        int ob = (t & 7) * 8;
        u16 vals[8] __attribute__((aligned(16)));
#pragma unroll
        for (int k = 0; k < 8; ++k) vals[k] = tile[ob + k][oc];
        u16* po = out + (long)blockIdx.z * N_ * C_ + (long)(c0 + oc) * C_ + r0 + ob;
        *(uint64_t*)po = *(const uint64_t*)vals;
        *(uint64_t*)(po + 4) = *(const uint64_t*)(vals + 4);
    }
}

// ---------------------------------------------------------------------------
// gemm_proj: Out = xT [BN,512] x W[z]^T [256,512] + bias[z].  128x128 tile,
// BK=64 (8 K-steps, 32 MFMA/wave between barriers as 2 kh sub-iterations).
// XCD-grouped flat grid 1200: xcd=id&7, j=id>>3, xt=xcd+8*(j/6), yz=j%6
// (y=yz&1, z=yz>>1); xt>=196 -> early return.
// z=0 -> th, z=1 -> ph (row-major [BN][CI]); z=2 -> gT [B][CI][N] via an
// in-LDS transpose of the output tile.
// Fragment-order DMA staging, dbuf. block = 256.
// LDS: staging 64 KB; transpose tile 33 KB aliases into it -> smem[32768].
// ---------------------------------------------------------------------------
__global__ __launch_bounds__(256, 2) void gemm_proj(
    const u16* __restrict__ A,        // xT [BN][C]
    const u16* __restrict__ BtBase,   // ctw (3 sets, stride 131328)
    u16* __restrict__ OutBase,        // th; ph = +ostride
    u16* __restrict__ gT,             // [B][CI][N]
    long ostride)
{
    __shared__ __attribute__((aligned(16))) u16 smem[32768];  // 65536 B
    const int t = threadIdx.x;
    const int wave = t >> 6, lane = t & 63;
    const int q = lane >> 4, lx = lane & 15;
    // XCD-grouped decode
    const int id = blockIdx.x;
    const int xcd = id & 7;
    const int j6 = id >> 3;                  // 0..149
    const int xt = xcd + 8 * (j6 / 6);
    if (xt >= 196) return;
    const int yz = j6 % 6;
    const int m0 = xt * 128;
    const int n0 = (yz & 1) * 128;           // ci tile base
    const int zz = yz >> 1;
    const u16* Bt = BtBase + (long)zz * 131328L;
    const u16* bias = Bt + 131072;

    // BK=64 staging: buf(2) x kh(2) x rg(8) x 512 u16
    auto As = [&](int buf, int kh, int rg) -> u16* {
        return smem + ((buf * 2 + kh) * 8 + rg) * 512; };
    auto Bs = [&](int buf, int kh, int rg) -> u16* {
        return smem + 16384 + ((buf * 2 + kh) * 8 + rg) * 512; };

    floatx4 zero4 = {0.f, 0.f, 0.f, 0.f};
    floatx4 acc[4][4];
#pragma unroll
    for (int i = 0; i < 4; ++i)
#pragma unroll
        for (int j = 0; j < 4; ++j) acc[i][j] = zero4;

    auto stage = [&](int buf, int k0) {
#pragma unroll
        for (int i = 0; i < 2; ++i) {
            int rg = wave * 2 + i;
#pragma unroll
            for (int kh = 0; kh < 2; ++kh) {
                gload_lds16(A + (long)(m0 + rg * 16 + lx) * C_ + k0 + kh * 32 + q * 8,
                            As(buf, kh, rg));
                gload_lds16(Bt + (long)(n0 + rg * 16 + lx) * C_ + k0 + kh * 32 + q * 8,
                            Bs(buf, kh, rg));
            }
        }
    };

    stage(0, 0);
    const int rg0 = (wave >> 1) * 4, cg0 = (wave & 1) * 4;
    for (int s = 0; s < C_ / 64; ++s) {      // 8 steps
        const int buf = s & 1;
        __syncthreads();
        if (s + 1 < C_ / 64) stage(buf ^ 1, (s + 1) * 64);
#pragma unroll
        for (int kh = 0; kh < 2; ++kh) {
            short8 af[4], bfr[4];
#pragma unroll
            for (int i = 0; i < 4; ++i)
                af[i] = *(const short8*)(As(buf, kh, rg0 + i) + lane * 8);
#pragma unroll
            for (int j = 0; j < 4; ++j)
                bfr[j] = *(const short8*)(Bs(buf, kh, cg0 + j) + lane * 8);
#pragma unroll
            for (int i = 0; i < 4; ++i)
#pragma unroll
                for (int j = 0; j < 4; ++j)
                    acc[i][j] = mfma16(af[i], bfr[j], acc[i][j]);
        }
    }

    // C/D layout: col=lane&15, row=(lane>>4)*4+reg  [m89/m91]
    const int wr = (wave >> 1) * 64, wc = (wave & 1) * 64;
    if (zz < 2) {
        u16* Out = OutBase + (long)zz * ostride;
#pragma unroll
        for (int j = 0; j < 4; ++j) {
            int col = n0 + wc + j * 16 + lx;
            float bv = b2f(bias[col]);
#pragma unroll
            for (int i = 0; i < 4; ++i)
#pragma unroll
                for (int r = 0; r < 4; ++r) {
                    int row = m0 + wr + i * 16 + q * 4 + r;
                    Out[(long)row * CI_ + col] = f2b(acc[i][j][r] + bv);
                }
        }
    } else {
        __syncthreads();   // all staging reads done before LDS reuse
        // phase 1: tile[ci_local][n_local], pitch 132
#pragma unroll
        for (int j = 0; j < 4; ++j) {
            int cl = wc + j * 16 + lx;
            float bv = b2f(bias[n0 + cl]);
#pragma unroll
            for (int i = 0; i < 4; ++i)
#pragma unroll
                for (int r = 0; r < 4; ++r)
                    smem[cl * 132 + wr + i * 16 + q * 4 + r] =
                        f2b(acc[i][j][r] + bv);
        }
        __syncthreads();
        // phase 2: coalesced 16-n runs to gT (N%16==0 -> no batch straddle)
#pragma unroll
        for (int p = 0; p < 4; ++p) {
            int cc = (t >> 3) + p * 32;
            int nn0 = (t & 7) * 16;
            u16 vals[16] __attribute__((aligned(16)));
#pragma unroll
            for (int k = 0; k < 16; ++k) vals[k] = smem[cc * 132 + nn0 + k];
            int m = m0 + nn0;
            int bb = m / N_;
            int nn = m - bb * N_;
            u16* dst = gT + ((long)bb * CI_ + (n0 + cc)) * N_ + nn;
            *(short8*)dst = *(const short8*)&vals[0];
            *(short8*)(dst + 8) = *(const short8*)&vals[8];
        }
    }
}

// ---------------------------------------------------------------------------
// Fused attention (R14 structure, z-split 2, XCD-grouped dispatch):
// flat grid 400; decode b = id&7, k = id>>3, z = k>=25, xb = k-25z.
// With round-robin id%8 -> XCD, all 50 blocks of batch b share XCD b, so
// the 25 lockstep sharers of each (b,z) phi/g step-slice hit one L2.
// Body otherwise IDENTICAL to R14/R17: swapped QK^T, in-register
// cvt_pk/permlane transpose, full dbuf psf+gsf, ONE __syncthreads per
// step, setprio on MFMA clusters, ones-MFMA row sums.
// grid = (400), block = 256.  LDS = 64 KB.  m-chunk = 1568 = 49x32.
// ---------------------------------------------------------------------------
__global__ __launch_bounds__(256, 2) void attn(
    const u16* __restrict__ theta,   // [B][N][CI]
    const u16* __restrict__ phi,     // [B][N][CI]
    const u16* __restrict__ gT,      // [B][CI][N]
    u16* __restrict__ yp0, u16* __restrict__ yp1,
    float* __restrict__ lpart)       // [2][B][N] row exp-sums
{
    __shared__ __attribute__((aligned(16))) u16 psf[2][8][2][64][8];
    __shared__ __attribute__((aligned(16))) u16 gsf[2][16][64][8];

    const int t = threadIdx.x;
    const int wave = t >> 6, lane = t & 63;
    const int q = lane >> 4, lx = lane & 15;
    // XCD-grouped decode: id%8 = b -> all of batch b on one XCD.
    const int id = blockIdx.x;
    const int b = id & 7;
    const int k8 = id >> 3;              // 0..49
    const int z = (k8 >= 25) ? 1 : 0;
    const int xb = k8 - z * 25;          // 0..24
    const int n0w = xb * 128 + wave * 32;
    const bool valid = n0w < N_;
    const u16* thb = theta + (long)b * N_ * CI_;
    const u16* phb = phi + (long)b * N_ * CI_;
    const u16* gb = gT + (long)b * CI_ * N_;

    short8 tf[2][8];
#pragma unroll
    for (int h = 0; h < 2; ++h) {
        int trow = n0w + h * 16 + lx;
        if (trow >= N_) trow = N_ - 1;
#pragma unroll
        for (int kk = 0; kk < 8; ++kk)
            tf[h][kk] = *(const short8*)(thb + (long)trow * CI_ + kk * 32 + q * 8);
    }

    floatx4 zero4 = {0.f, 0.f, 0.f, 0.f};
    floatx4 yacc[2][16];
#pragma unroll
    for (int h = 0; h < 2; ++h)
#pragma unroll
        for (int i = 0; i < 16; ++i) yacc[h][i] = zero4;
    floatx4 lacc[2] = {zero4, zero4};
    const short8 ones = {0x3F80, 0x3F80, 0x3F80, 0x3F80,
                         0x3F80, 0x3F80, 0x3F80, 0x3F80};

    const int mbeg = z * 1568;               // 1568 = 49 * 32; 2*1568 = N_

    auto stage = [&](int buf, int m0) {
#pragma unroll
        for (int i = 0; i < 2; ++i) {
            int kc = wave * 2 + i;
#pragma unroll
            for (int h = 0; h < 2; ++h)
                gload_lds16(phb + (long)(m0 + h * 16 + lx) * CI_ + kc * 32 + q * 8,
                            &psf[buf][kc][h][0][0]);
        }
#pragma unroll
        for (int j4 = 0; j4 < 4; ++j4) {
            int ct = wave * 4 + j4;
            gload_lds16(gb + (long)(ct * 16 + lx) * N_ + m0 + q * 8,
                        &gsf[buf][ct][0][0]);
        }
    };

    stage(0, mbeg);
    const int NSTEP = 49;
    for (int s = 0; s < NSTEP; ++s) {
        const int buf = s & 1;
        __syncthreads();
        if (s + 1 < NSTEP) stage(buf ^ 1, mbeg + (s + 1) * 32);

        // QK^T, swapped operands: sacc[h][mh] = S^T quadrant
        //   lane(q,lx) reg r  <->  m_local = mh*16 + q*4 + r, n_local = h*16 + lx
        floatx4 sacc[2][2];
        sacc[0][0] = zero4; sacc[0][1] = zero4;
        sacc[1][0] = zero4; sacc[1][1] = zero4;
        __builtin_amdgcn_s_setprio(1);
#pragma unroll
        for (int kk = 0; kk < 8; ++kk) {
            short8 bf0 = *(const short8*)&psf[buf][kk][0][lane][0];
            short8 bf1 = *(const short8*)&psf[buf][kk][1][lane][0];
            sacc[0][0] = mfma16(bf0, tf[0][kk], sacc[0][0]);
            sacc[1][0] = mfma16(bf0, tf[1][kk], sacc[1][0]);
            sacc[0][1] = mfma16(bf1, tf[0][kk], sacc[0][1]);
            sacc[1][1] = mfma16(bf1, tf[1][kk], sacc[1][1]);
        }
        __builtin_amdgcn_s_setprio(0);

        // exp + in-register transpose to PV A-fragments.
        // pA[h] lane(q,lx) = P[n = h*16+lx][m = q*8 .. q*8+7] as 8 bf16.
        short8 pA[2];
#pragma unroll
        for (int h = 0; h < 2; ++h) {
            float e0 = __expf(fminf(sacc[h][0][0], 60.f));
            float e1 = __expf(fminf(sacc[h][0][1], 60.f));
            float e2 = __expf(fminf(sacc[h][0][2], 60.f));
            float e3 = __expf(fminf(sacc[h][0][3], 60.f));
            float f0 = __expf(fminf(sacc[h][1][0], 60.f));
            float f1 = __expf(fminf(sacc[h][1][1], 60.f));
            float f2 = __expf(fminf(sacc[h][1][2], 60.f));
            float f3 = __expf(fminf(sacc[h][1][3], 60.f));
            u32 A0, A1, B0, B1;
            asm("v_cvt_pk_bf16_f32 %0, %1, %2" : "=v"(A0) : "v"(e0), "v"(e1));
            asm("v_cvt_pk_bf16_f32 %0, %1, %2" : "=v"(A1) : "v"(e2), "v"(e3));
            asm("v_cvt_pk_bf16_f32 %0, %1, %2" : "=v"(B0) : "v"(f0), "v"(f1));
            asm("v_cvt_pk_bf16_f32 %0, %1, %2" : "=v"(B1) : "v"(f2), "v"(f3));
            // swap32: X' = [Xq0,Xq1,Yq0,Yq1], Y' = [Xq2,Xq3,Yq2,Yq3]
            asm("v_permlane32_swap_b32 %0, %1" : "+v"(A0), "+v"(B0));
            asm("v_permlane32_swap_b32 %0, %1" : "+v"(A1), "+v"(B1));
            // swap16: X''= [X'q0,Y'q0,X'q2,Y'q2], Y''= [X'q1,Y'q1,X'q3,Y'q3]
            asm("v_permlane16_swap_b32 %0, %1" : "+v"(A0), "+v"(B0));
            asm("v_permlane16_swap_b32 %0, %1" : "+v"(A1), "+v"(B1));
            // dwords: d0 = A0 (m q*8+0,1), d1 = A1 (+2,3),
            //         d2 = B0 (+4,5),      d3 = B1 (+6,7)
            uint4v pk;
            pk[0] = A0; pk[1] = A1; pk[2] = B0; pk[3] = B1;
            pA[h] = __builtin_bit_cast(short8, pk);
        }

        __builtin_amdgcn_s_setprio(1);
#pragma unroll
        for (int ct = 0; ct < 16; ++ct) {
            short8 gf = *(const short8*)&gsf[buf][ct][lane][0];
            yacc[0][ct] = mfma16(pA[0], gf, yacc[0][ct]);
            yacc[1][ct] = mfma16(pA[1], gf, yacc[1][ct]);
        }
        lacc[0] = mfma16(pA[0], ones, lacc[0]);
        lacc[1] = mfma16(pA[1], ones, lacc[1]);
        __builtin_amdgcn_s_setprio(0);
    }

    if (valid) {
        u16* ypz = (z == 0) ? yp0 : yp1;
        u16* yb = ypz + (long)b * N_ * CI_;
#pragma unroll
        for (int h = 0; h < 2; ++h)
#pragma unroll
            for (int ct = 0; ct < 16; ++ct)
#pragma unroll
                for (int r = 0; r < 4; ++r)
                    yb[(long)(n0w + h * 16 + q * 4 + r) * CI_ + ct * 16 + lx] =
                        f2b(yacc[h][ct][r]);
        if (lx == 0) {
#pragma unroll
            for (int h = 0; h < 2; ++h)
#pragma unroll
                for (int r = 0; r < 4; ++r)
                    lpart[(long)z * BN_ + (long)b * N_ + n0w + h * 16 + q * 4 + r] =
                        lacc[h][r];
        }
    }
}

// ---------------------------------------------------------------------------
// gemm_w (n-paired): wy[m][c] = sum_k y[m][k]*Wt[c][k] + wb[c], where
// y = (yp0+yp1)[m][k] / l[m] combined on the fly. Each block computes a
// 128x256 output: acc[4][8] (128 accumulators, AGPR side). Bsf 16 row
// groups (32 KB), Asf unchanged (16 KB) -> 48 KB LDS, launch (256,2).
// XCD-grouped flat grid 400: xcd=id&7, j=id>>3, xt=xcd+8*(j>>1),
// n0=(j&1)*256; xt>=196 -> early return.
// Also accumulates per-channel BN sums (stats) via shfl + atomics.
// ---------------------------------------------------------------------------
__global__ __launch_bounds__(256, 2) void gemm_w(
    const u16* __restrict__ yp0, const u16* __restrict__ yp1,
    const float* __restrict__ lpart,
    const u16* __restrict__ Bt,       // cww [512][256]
    const u16* __restrict__ bias,     // cwb [512]
    u16* __restrict__ wy,             // [BN][512]
    float* __restrict__ stats)
{
    __shared__ __attribute__((aligned(16))) u16 Asf[2][8][64][8];   // 16 KB
    __shared__ __attribute__((aligned(16))) u16 Bsf[2][16][64][8];  // 32 KB

    const int t = threadIdx.x;
    const int wave = t >> 6, lane = t & 63;
    const int q = lane >> 4, lx = lane & 15;
    // XCD-grouped decode
    const int id = blockIdx.x;
    const int xcd = id & 7;
    const int j2 = id >> 3;              // 0..49
    const int xt = xcd + 8 * (j2 >> 1);
    if (xt >= 196) return;
    const int m0 = xt * 128;
    const int n0 = (j2 & 1) * 256;

    float rl[2];
#pragma unroll
    for (int i = 0; i < 2; ++i) {
        int row = m0 + (wave * 2 + i) * 16 + lx;
        rl[i] = 1.0f / (lpart[row] + lpart[BN_ + row]);
    }

    floatx4 zero4 = {0.f, 0.f, 0.f, 0.f};
    floatx4 acc[4][8];
#pragma unroll
    for (int i = 0; i < 4; ++i)
#pragma unroll
        for (int j = 0; j < 8; ++j) acc[i][j] = zero4;

    short8 va[2][2];
    auto loadA = [&](int k0) {
#pragma unroll
        for (int i = 0; i < 2; ++i) {
            long off = (long)(m0 + (wave * 2 + i) * 16 + lx) * CI_ + k0 + q * 8;
            va[i][0] = *(const short8*)(yp0 + off);
            va[i][1] = *(const short8*)(yp1 + off);
        }
    };
    auto writeA = [&](int buf) {
#pragma unroll
        for (int i = 0; i < 2; ++i) {
            u16 pk[8] __attribute__((aligned(16)));
#pragma unroll
            for (int e = 0; e < 8; ++e) {
                float v = (b2f(((const u16*)&va[i][0])[e]) +
                           b2f(((const u16*)&va[i][1])[e])) * rl[i];
                pk[e] = f2b(v);
            }
            *(short8*)&Asf[buf][wave * 2 + i][lane][0] = *(const short8*)pk;
        }
    };
    auto stageB = [&](int buf, int k0) {
#pragma unroll
        for (int i = 0; i < 4; ++i) {
            int rg = wave * 4 + i;
            gload_lds16(Bt + (long)(n0 + rg * 16 + lx) * CI_ + k0 + q * 8,
                        &Bsf[buf][rg][0][0]);
        }
    };

    loadA(0); writeA(0); stageB(0, 0);
    const int rg0 = (wave >> 1) * 4, cg0 = (wave & 1) * 8;
    const int NS = CI_ / 32;   // 8
    for (int s = 0; s < NS; ++s) {
        const int buf = s & 1;
        __syncthreads();
        if (s + 1 < NS) { loadA((s + 1) * 32); stageB(buf ^ 1, (s + 1) * 32); }
        short8 af[4];
#pragma unroll
        for (int i = 0; i < 4; ++i)
            af[i] = *(const short8*)&Asf[buf][rg0 + i][lane][0];
#pragma unroll
        for (int j = 0; j < 8; ++j) {
            short8 bfr = *(const short8*)&Bsf[buf][cg0 + j][lane][0];
#pragma unroll
            for (int i = 0; i < 4; ++i)
                acc[i][j] = mfma16(af[i], bfr, acc[i][j]);
        }
        if (s + 1 < NS) writeA(buf ^ 1);
    }

    // epilogue: bias, wy write, fused BN channel partials
    const int wr = (wave >> 1) * 64, wc = (wave & 1) * 128;
#pragma unroll
    for (int j = 0; j < 8; ++j) {
        int col = n0 + wc + j * 16 + lx;
        float bv = b2f(bias[col]);
        float cs = 0.f, cq = 0.f;
#pragma unroll
        for (int i = 0; i < 4; ++i)
#pragma unroll
            for (int r = 0; r < 4; ++r) {
                int row = m0 + wr + i * 16 + q * 4 + r;
                float v = acc[i][j][r] + bv;
                wy[(long)row * C_ + col] = f2b(v);
                cs += v; cq += v * v;
            }
        cs += __shfl_xor(cs, 16); cs += __shfl_xor(cs, 32);
        cq += __shfl_xor(cq, 16); cq += __shfl_xor(cq, 32);
        if (q == 0) {
            atomicAdd(&stats[col], cs);
            atomicAdd(&stats[C_ + col], cq);
        }
    }
}

// ---------------------------------------------------------------------------
// out[b][c][n] = (wy[b][n][c]-mean)*rstd*gamma + beta + xT[b][n][c]
// Residual read from xT (bf16, same [row][col] layout as wy -> same
// coalesced tile pass); x itself only read for the 4KB dtype flag.
// ---------------------------------------------------------------------------
__global__ __launch_bounds__(256) void bn_apply(
    const u16* __restrict__ wy, const u16* __restrict__ xT,
    const void* __restrict__ xv,
    const u16* __restrict__ gamma, const u16* __restrict__ beta,
    const float* __restrict__ stats, void* __restrict__ outv)
{
    const int fl = block_flag(xv);
    __shared__ float tile[64][65];
    __shared__ float tx[64][65];
    const int t = threadIdx.x;
    const int nb0 = blockIdx.x * 64;
    const int c0 = blockIdx.y * 64;
    const int b = blockIdx.z;
#pragma unroll
    for (int j = 0; j < 4; ++j) {
        int row = (t >> 4) + 16 * j;
        int col = (t & 15) * 4;
        long off = ((long)b * N_ + nb0 + row) * C_ + c0 + col;
        u16 lv[4] __attribute__((aligned(8)));
        u16 lx4[4] __attribute__((aligned(8)));
        *(uint64_t*)lv = *(const uint64_t*)(wy + off);
        *(uint64_t*)lx4 = *(const uint64_t*)(xT + off);
#pragma unroll
        for (int k = 0; k < 4; ++k) {
            tile[row][col + k] = b2f(lv[k]);
            tx[row][col + k] = b2f(lx4[k]);
        }
    }
    __syncthreads();
    const float inv = 1.0f / (float)BN_;
#pragma unroll
    for (int it = 0; it < 8; ++it) {
        int oc = (t >> 5) + 8 * it;
        int on = (t & 31) * 2;
        int c = c0 + oc;
        float mean = stats[c] * inv;
        float var = stats[C_ + c] * inv - mean * mean;
        float rstd = rsqrtf(var + 1e-5f);
        float sc = b2f(gamma[c]) * rstd;
        float sh = b2f(beta[c]) - mean * sc;
        long base = ((long)b * C_ + c) * N_ + nb0 + on;
        float v0 = tile[on][oc] * sc + sh + tx[on][oc];
        float v1 = tile[on + 1][oc] * sc + sh + tx[on + 1][oc];
        if (fl) {
            ((u16*)outv)[base] = f2b(v0);
            ((u16*)outv)[base + 1] = f2b(v1);
        } else {
            ((float*)outv)[base] = v0;
            ((float*)outv)[base + 1] = v1;
        }
    }
}

// ---------------------------------------------------------------------------
extern "C" void kernel_launch(void* const* d_in, const int* in_sizes, int n_in,
                              void* d_out, int out_size, void* d_ws, size_t ws_size,
                              hipStream_t stream)
{
    (void)in_sizes; (void)n_in; (void)out_size; (void)ws_size;

    const size_t S = 12845056;               // one [B,N,CI] bf16 slab (bytes)
    const size_t SE = S / 2;                 // slab element count
    char* base = (char*)d_ws;
    u16*   xT    = (u16*)(base);             // [0, 2S)  convert->proj->bn_apply
    u16*   th    = (u16*)(base + 2 * S);     // [2S, 3S) proj->attn (ph=+SE)
    u16*   wy    = (u16*)(base + 2 * S);     // [2S, 4S) gemm_w->bn_apply
    u16*   gT    = (u16*)(base + 4 * S);     // [4S, 5S) proj->attn
    float* lpart = (float*)(base + 5 * S);                          // 200 KB
    float* stats = (float*)(base + 5 * S + (size_t)4 * BN_ * 4);
    u16*   cw    = (u16*)(base + 5 * S + (size_t)4 * BN_ * 4 + 4096);

    // canonical param offsets (convert_params segment order)
    u16* ctw = cw;
    u16* cww = cw + 393984;
    u16* cwb = cw + 525056;
    u16* cga = cw + 525568;
    u16* cbe = cw + 526080;

    u16* yp0 = (u16*)d_out;             // d_out = 2 slabs of scratch
    u16* yp1 = (u16*)d_out + SE;        // dead before bn_apply overwrites

    convert_params<<<dim3(64, 10), 256, 0, stream>>>(
        d_in[0], d_in[1], d_in[2], d_in[3], d_in[4], d_in[5], d_in[6],
        d_in[7], d_in[8], d_in[9], d_in[10], cw, stats);

    transpose_x<<<dim3(N_ / 64, C_ / 64, B_), 256, 0, stream>>>(d_in[0], xT);

    // fused theta/phi/g projections (XCD-grouped flat grid); g -> gT
    gemm_proj<<<dim3(1200, 1, 1), 256, 0, stream>>>(
        xT, ctw, th, gT, (long)SE);

    // XCD-grouped flat grid (decode inside kernel)
    attn<<<dim3(400, 1, 1), 256, 0, stream>>>(
        th, th + SE, gT, yp0, yp1, lpart);

    // W GEMM, n-paired (128x256 per block), XCD-grouped
    gemm_w<<<dim3(400, 1, 1), 256, 0, stream>>>(
        yp0, yp1, lpart, cww, cwb, wy, stats);

    bn_apply<<<dim3(N_ / 64, C_ / 64, B_), 256, 0, stream>>>(
        wy, xT, d_in[0], cga, cbe, stats, d_out);
}

// Round 14
// 333.802 us; speedup vs baseline: 1.0236x; 1.0236x over previous
//
#include <hip/hip_runtime.h>
#include <hip/hip_bf16.h>

// NonLocalBlock: B=8, C=512, CI=256, H=W=56, N=3136.
// Round-23: bn_apply fixed — R22's xT-residual kept, but the BN affine +
// residual are folded into the LOAD phase so only ONE float[64][65] tile
// is needed (R22's second tile doubled LDS to 33 KB and halved occupancy,
// costing more than the 52 MB read saving). Per-thread sc/sh computed once
// (4 fixed channels), phase-2 is a pure transposed write.
// Everything else frozen: attn R19, gemm_proj R20 (BK=64), gemm_w R21
// (n-paired), all XCD-grouped.
// Dispatches (6): convert_params, transpose_x, gemm_proj, attn, gemm_w,
// bn_apply.

typedef unsigned short u16;
typedef unsigned int u32;
typedef __attribute__((ext_vector_type(8))) short short8;   // 8 bf16
typedef __attribute__((ext_vector_type(4))) float floatx4;
typedef __attribute__((ext_vector_type(4))) u32 uint4v;

#define B_   8
#define C_   512
#define CI_  256
#define N_   3136
#define BN_  25088   // B_*N_

__device__ __forceinline__ u16 f2b(float f) {
    return __builtin_bit_cast(u16, __float2bfloat16(f));
}
__device__ __forceinline__ float b2f(u16 u) {
    return __bfloat162float(__builtin_bit_cast(__hip_bfloat16, u));
}
__device__ __forceinline__ floatx4 mfma16(short8 a, short8 b, floatx4 c) {
    return __builtin_amdgcn_mfma_f32_16x16x32_bf16(a, b, c, 0, 0, 0);
}
// async global->LDS DMA, 16 B/lane; LDS dest = wave-uniform base + lane*16,
// source address fully per-lane (gather).
__device__ __forceinline__ void gload_lds16(const u16* g, u16* l) {
    __builtin_amdgcn_global_load_lds(
        (const __attribute__((address_space(1))) u32*)g,
        (__attribute__((address_space(3))) u32*)l, 16, 0, 0);
}

// Per-block dtype flag from a 4KB x prefix (bf16-pair vs fp32 mantissa noise).
// Call at kernel top with all 256 threads active.
__device__ __forceinline__ int block_flag(const void* x) {
    __shared__ int cnt_;
    if (threadIdx.x == 0) cnt_ = 0;
    __syncthreads();
    const u32* xw = (const u32*)x;
    int c = 0;
#pragma unroll
    for (int i = 0; i < 4; ++i) {
        u32 w = xw[threadIdx.x * 4 + i];
        u32 e = (w >> 7) & 0xFF;
        c += (e >= 118 && e <= 130) ? 1 : 0;
    }
    atomicAdd(&cnt_, c);
    __syncthreads();
    return (2 * cnt_ > 1024) ? 1 : 0;
}

// ---------------------------------------------------------------------------
// Convert 10 parameter arrays into canonical bf16 (flag inline).
// Block (0,0) additionally zeroes the BN stats buffer.
// ---------------------------------------------------------------------------
__global__ __launch_bounds__(256) void convert_params(
    const void* __restrict__ x,
    const void* tw, const void* tb, const void* pw, const void* pb,
    const void* gw, const void* gbi, const void* ww, const void* wb,
    const void* gamma, const void* beta,
    u16* __restrict__ dst, float* __restrict__ stats)
{
    const int fl = block_flag(x);
    if (blockIdx.x == 0 && blockIdx.y == 0) {
        stats[threadIdx.x] = 0.f;
        stats[threadIdx.x + 256] = 0.f;
        stats[threadIdx.x + 512] = 0.f;
        stats[threadIdx.x + 768] = 0.f;
    }
    const void* srcs[10] = {tw, tb, pw, pb, gw, gbi, ww, wb, gamma, beta};
    const int ns[10] = {131072, 256, 131072, 256, 131072, 256, 131072, 512, 512, 512};
    int seg = blockIdx.y;
    int off = 0;
    for (int s = 0; s < 10; ++s) { if (s == seg) break; off += ns[s]; }
    const void* src = srcs[seg];
    int n = ns[seg];
    int i0 = (blockIdx.x * 256 + threadIdx.x) * 8;
    if (i0 >= n) return;
    u16* d = dst + off;
    for (int k = 0; k < 8; ++k) {
        int i = i0 + k;
        if (i < n)
            d[i] = fl ? ((const u16*)src)[i] : f2b(((const float*)src)[i]);
    }
}

// ---------------------------------------------------------------------------
// x ingest + transpose: x [b,C,N] (fp32 or bf16) -> xT [b,N,C] bf16.
// ---------------------------------------------------------------------------
__global__ __launch_bounds__(256) void transpose_x(
    const void* __restrict__ in, u16* __restrict__ out)
{
    const int fl = block_flag(in);
    __shared__ u16 tile[64][68];
    const int t = threadIdx.x;
    const long base = (long)blockIdx.z * (long)C_ * (long)N_;
    const int c0 = blockIdx.x * 64, r0 = blockIdx.y * 64;
    const int lr = t >> 3;
    const int lc = (t & 7) * 8;
#pragma unroll
    for (int j = 0; j < 2; ++j) {
        int rr = lr + 32 * j;
        long eoff = base + (long)(r0 + rr) * N_ + c0 + lc;
        u16 v[8] __attribute__((aligned(16)));
        if (fl) {
            const u16* pi = (const u16*)in + eoff;
            *(uint64_t*)&v[0] = *(const uint64_t*)pi;
            *(uint64_t*)&v[4] = *(const uint64_t*)(pi + 4);
        } else {
            const float* pi = (const float*)in + eoff;
            floatx4 a = *(const floatx4*)pi;
            floatx4 b4 = *(const floatx4*)(pi + 4);
#pragma unroll
            for (int k = 0; k < 4; ++k) { v[k] = f2b(a[k]); v[4 + k] = f2b(b4[k]); }
        }
        *(uint64_t*)&tile[rr][lc] = *(const uint64_t*)&v[0];
        *(uint64_t*)&tile[rr][lc + 4] = *(const uint64_t*)&v[4];
    }
    __syncthreads();
#pragma unroll
    for (int j = 0; j < 2; ++j) {
        int oc = lr + 32 * j;
        int ob = (t & 7) * 8;
        u16 vals[8] __attribute__((aligned(16)));
#pragma unroll
        for (int k = 0; k < 8; ++k) vals[k] = tile[ob + k][oc];
        u16* po = out + (long)blockIdx.z * N_ * C_ + (long)(c0 + oc) * C_ + r0 + ob;
        *(uint64_t*)po = *(const uint64_t*)vals;
        *(uint64_t*)(po + 4) = *(const uint64_t*)(vals + 4);
    }
}

// ---------------------------------------------------------------------------
// gemm_proj: Out = xT [BN,512] x W[z]^T [256,512] + bias[z].  128x128 tile,
// BK=64 (8 K-steps, 32 MFMA/wave between barriers as 2 kh sub-iterations).
// XCD-grouped flat grid 1200: xcd=id&7, j=id>>3, xt=xcd+8*(j/6), yz=j%6
// (y=yz&1, z=yz>>1); xt>=196 -> early return.
// z=0 -> th, z=1 -> ph (row-major [BN][CI]); z=2 -> gT [B][CI][N] via an
// in-LDS transpose of the output tile.
// Fragment-order DMA staging, dbuf. block = 256.
// LDS: staging 64 KB; transpose tile 33 KB aliases into it -> smem[32768].
// ---------------------------------------------------------------------------
__global__ __launch_bounds__(256, 2) void gemm_proj(
    const u16* __restrict__ A,        // xT [BN][C]
    const u16* __restrict__ BtBase,   // ctw (3 sets, stride 131328)
    u16* __restrict__ OutBase,        // th; ph = +ostride
    u16* __restrict__ gT,             // [B][CI][N]
    long ostride)
{
    __shared__ __attribute__((aligned(16))) u16 smem[32768];  // 65536 B
    const int t = threadIdx.x;
    const int wave = t >> 6, lane = t & 63;
    const int q = lane >> 4, lx = lane & 15;
    // XCD-grouped decode
    const int id = blockIdx.x;
    const int xcd = id & 7;
    const int j6 = id >> 3;                  // 0..149
    const int xt = xcd + 8 * (j6 / 6);
    if (xt >= 196) return;
    const int yz = j6 % 6;
    const int m0 = xt * 128;
    const int n0 = (yz & 1) * 128;           // ci tile base
    const int zz = yz >> 1;
    const u16* Bt = BtBase + (long)zz * 131328L;
    const u16* bias = Bt + 131072;

    // BK=64 staging: buf(2) x kh(2) x rg(8) x 512 u16
    auto As = [&](int buf, int kh, int rg) -> u16* {
        return smem + ((buf * 2 + kh) * 8 + rg) * 512; };
    auto Bs = [&](int buf, int kh, int rg) -> u16* {
        return smem + 16384 + ((buf * 2 + kh) * 8 + rg) * 512; };

    floatx4 zero4 = {0.f, 0.f, 0.f, 0.f};
    floatx4 acc[4][4];
#pragma unroll
    for (int i = 0; i < 4; ++i)
#pragma unroll
        for (int j = 0; j < 4; ++j) acc[i][j] = zero4;

    auto stage = [&](int buf, int k0) {
#pragma unroll
        for (int i = 0; i < 2; ++i) {
            int rg = wave * 2 + i;
#pragma unroll
            for (int kh = 0; kh < 2; ++kh) {
                gload_lds16(A + (long)(m0 + rg * 16 + lx) * C_ + k0 + kh * 32 + q * 8,
                            As(buf, kh, rg));
                gload_lds16(Bt + (long)(n0 + rg * 16 + lx) * C_ + k0 + kh * 32 + q * 8,
                            Bs(buf, kh, rg));
            }
        }
    };

    stage(0, 0);
    const int rg0 = (wave >> 1) * 4, cg0 = (wave & 1) * 4;
    for (int s = 0; s < C_ / 64; ++s) {      // 8 steps
        const int buf = s & 1;
        __syncthreads();
        if (s + 1 < C_ / 64) stage(buf ^ 1, (s + 1) * 64);
#pragma unroll
        for (int kh = 0; kh < 2; ++kh) {
            short8 af[4], bfr[4];
#pragma unroll
            for (int i = 0; i < 4; ++i)
                af[i] = *(const short8*)(As(buf, kh, rg0 + i) + lane * 8);
#pragma unroll
            for (int j = 0; j < 4; ++j)
                bfr[j] = *(const short8*)(Bs(buf, kh, cg0 + j) + lane * 8);
#pragma unroll
            for (int i = 0; i < 4; ++i)
#pragma unroll
                for (int j = 0; j < 4; ++j)
                    acc[i][j] = mfma16(af[i], bfr[j], acc[i][j]);
        }
    }

    // C/D layout: col=lane&15, row=(lane>>4)*4+reg  [m89/m91]
    const int wr = (wave >> 1) * 64, wc = (wave & 1) * 64;
    if (zz < 2) {
        u16* Out = OutBase + (long)zz * ostride;
#pragma unroll
        for (int j = 0; j < 4; ++j) {
            int col = n0 + wc + j * 16 + lx;
            float bv = b2f(bias[col]);
#pragma unroll
            for (int i = 0; i < 4; ++i)
#pragma unroll
                for (int r = 0; r < 4; ++r) {
                    int row = m0 + wr + i * 16 + q * 4 + r;
                    Out[(long)row * CI_ + col] = f2b(acc[i][j][r] + bv);
                }
        }
    } else {
        __syncthreads();   // all staging reads done before LDS reuse
        // phase 1: tile[ci_local][n_local], pitch 132
#pragma unroll
        for (int j = 0; j < 4; ++j) {
            int cl = wc + j * 16 + lx;
            float bv = b2f(bias[n0 + cl]);
#pragma unroll
            for (int i = 0; i < 4; ++i)
#pragma unroll
                for (int r = 0; r < 4; ++r)
                    smem[cl * 132 + wr + i * 16 + q * 4 + r] =
                        f2b(acc[i][j][r] + bv);
        }
        __syncthreads();
        // phase 2: coalesced 16-n runs to gT (N%16==0 -> no batch straddle)
#pragma unroll
        for (int p = 0; p < 4; ++p) {
            int cc = (t >> 3) + p * 32;
            int nn0 = (t & 7) * 16;
            u16 vals[16] __attribute__((aligned(16)));
#pragma unroll
            for (int k = 0; k < 16; ++k) vals[k] = smem[cc * 132 + nn0 + k];
            int m = m0 + nn0;
            int bb = m / N_;
            int nn = m - bb * N_;
            u16* dst = gT + ((long)bb * CI_ + (n0 + cc)) * N_ + nn;
            *(short8*)dst = *(const short8*)&vals[0];
            *(short8*)(dst + 8) = *(const short8*)&vals[8];
        }
    }
}

// ---------------------------------------------------------------------------
// Fused attention (R14 structure, z-split 2, XCD-grouped dispatch):
// flat grid 400; decode b = id&7, k = id>>3, z = k>=25, xb = k-25z.
// With round-robin id%8 -> XCD, all 50 blocks of batch b share XCD b, so
// the 25 lockstep sharers of each (b,z) phi/g step-slice hit one L2.
// Body otherwise IDENTICAL to R14/R17: swapped QK^T, in-register
// cvt_pk/permlane transpose, full dbuf psf+gsf, ONE __syncthreads per
// step, setprio on MFMA clusters, ones-MFMA row sums.
// grid = (400), block = 256.  LDS = 64 KB.  m-chunk = 1568 = 49x32.
// ---------------------------------------------------------------------------
__global__ __launch_bounds__(256, 2) void attn(
    const u16* __restrict__ theta,   // [B][N][CI]
    const u16* __restrict__ phi,     // [B][N][CI]
    const u16* __restrict__ gT,      // [B][CI][N]
    u16* __restrict__ yp0, u16* __restrict__ yp1,
    float* __restrict__ lpart)       // [2][B][N] row exp-sums
{
    __shared__ __attribute__((aligned(16))) u16 psf[2][8][2][64][8];
    __shared__ __attribute__((aligned(16))) u16 gsf[2][16][64][8];

    const int t = threadIdx.x;
    const int wave = t >> 6, lane = t & 63;
    const int q = lane >> 4, lx = lane & 15;
    // XCD-grouped decode: id%8 = b -> all of batch b on one XCD.
    const int id = blockIdx.x;
    const int b = id & 7;
    const int k8 = id >> 3;              // 0..49
    const int z = (k8 >= 25) ? 1 : 0;
    const int xb = k8 - z * 25;          // 0..24
    const int n0w = xb * 128 + wave * 32;
    const bool valid = n0w < N_;
    const u16* thb = theta + (long)b * N_ * CI_;
    const u16* phb = phi + (long)b * N_ * CI_;
    const u16* gb = gT + (long)b * CI_ * N_;

    short8 tf[2][8];
#pragma unroll
    for (int h = 0; h < 2; ++h) {
        int trow = n0w + h * 16 + lx;
        if (trow >= N_) trow = N_ - 1;
#pragma unroll
        for (int kk = 0; kk < 8; ++kk)
            tf[h][kk] = *(const short8*)(thb + (long)trow * CI_ + kk * 32 + q * 8);
    }

    floatx4 zero4 = {0.f, 0.f, 0.f, 0.f};
    floatx4 yacc[2][16];
#pragma unroll
    for (int h = 0; h < 2; ++h)
#pragma unroll
        for (int i = 0; i < 16; ++i) yacc[h][i] = zero4;
    floatx4 lacc[2] = {zero4, zero4};
    const short8 ones = {0x3F80, 0x3F80, 0x3F80, 0x3F80,
                         0x3F80, 0x3F80, 0x3F80, 0x3F80};

    const int mbeg = z * 1568;               // 1568 = 49 * 32; 2*1568 = N_

    auto stage = [&](int buf, int m0) {
#pragma unroll
        for (int i = 0; i < 2; ++i) {
            int kc = wave * 2 + i;
#pragma unroll
            for (int h = 0; h < 2; ++h)
                gload_lds16(phb + (long)(m0 + h * 16 + lx) * CI_ + kc * 32 + q * 8,
                            &psf[buf][kc][h][0][0]);
        }
#pragma unroll
        for (int j4 = 0; j4 < 4; ++j4) {
            int ct = wave * 4 + j4;
            gload_lds16(gb + (long)(ct * 16 + lx) * N_ + m0 + q * 8,
                        &gsf[buf][ct][0][0]);
        }
    };

    stage(0, mbeg);
    const int NSTEP = 49;
    for (int s = 0; s < NSTEP; ++s) {
        const int buf = s & 1;
        __syncthreads();
        if (s + 1 < NSTEP) stage(buf ^ 1, mbeg + (s + 1) * 32);

        // QK^T, swapped operands: sacc[h][mh] = S^T quadrant
        //   lane(q,lx) reg r  <->  m_local = mh*16 + q*4 + r, n_local = h*16 + lx
        floatx4 sacc[2][2];
        sacc[0][0] = zero4; sacc[0][1] = zero4;
        sacc[1][0] = zero4; sacc[1][1] = zero4;
        __builtin_amdgcn_s_setprio(1);
#pragma unroll
        for (int kk = 0; kk < 8; ++kk) {
            short8 bf0 = *(const short8*)&psf[buf][kk][0][lane][0];
            short8 bf1 = *(const short8*)&psf[buf][kk][1][lane][0];
            sacc[0][0] = mfma16(bf0, tf[0][kk], sacc[0][0]);
            sacc[1][0] = mfma16(bf0, tf[1][kk], sacc[1][0]);
            sacc[0][1] = mfma16(bf1, tf[0][kk], sacc[0][1]);
            sacc[1][1] = mfma16(bf1, tf[1][kk], sacc[1][1]);
        }
        __builtin_amdgcn_s_setprio(0);

        // exp + in-register transpose to PV A-fragments.
        // pA[h] lane(q,lx) = P[n = h*16+lx][m = q*8 .. q*8+7] as 8 bf16.
        short8 pA[2];
#pragma unroll
        for (int h = 0; h < 2; ++h) {
            float e0 = __expf(fminf(sacc[h][0][0], 60.f));
            float e1 = __expf(fminf(sacc[h][0][1], 60.f));
            float e2 = __expf(fminf(sacc[h][0][2], 60.f));
            float e3 = __expf(fminf(sacc[h][0][3], 60.f));
            float f0 = __expf(fminf(sacc[h][1][0], 60.f));
            float f1 = __expf(fminf(sacc[h][1][1], 60.f));
            float f2 = __expf(fminf(sacc[h][1][2], 60.f));
            float f3 = __expf(fminf(sacc[h][1][3], 60.f));
            u32 A0, A1, B0, B1;
            asm("v_cvt_pk_bf16_f32 %0, %1, %2" : "=v"(A0) : "v"(e0), "v"(e1));
            asm("v_cvt_pk_bf16_f32 %0, %1, %2" : "=v"(A1) : "v"(e2), "v"(e3));
            asm("v_cvt_pk_bf16_f32 %0, %1, %2" : "=v"(B0) : "v"(f0), "v"(f1));
            asm("v_cvt_pk_bf16_f32 %0, %1, %2" : "=v"(B1) : "v"(f2), "v"(f3));
            // swap32: X' = [Xq0,Xq1,Yq0,Yq1], Y' = [Xq2,Xq3,Yq2,Yq3]
            asm("v_permlane32_swap_b32 %0, %1" : "+v"(A0), "+v"(B0));
            asm("v_permlane32_swap_b32 %0, %1" : "+v"(A1), "+v"(B1));
            // swap16: X''= [X'q0,Y'q0,X'q2,Y'q2], Y''= [X'q1,Y'q1,X'q3,Y'q3]
            asm("v_permlane16_swap_b32 %0, %1" : "+v"(A0), "+v"(B0));
            asm("v_permlane16_swap_b32 %0, %1" : "+v"(A1), "+v"(B1));
            // dwords: d0 = A0 (m q*8+0,1), d1 = A1 (+2,3),
            //         d2 = B0 (+4,5),      d3 = B1 (+6,7)
            uint4v pk;
            pk[0] = A0; pk[1] = A1; pk[2] = B0; pk[3] = B1;
            pA[h] = __builtin_bit_cast(short8, pk);
        }

        __builtin_amdgcn_s_setprio(1);
#pragma unroll
        for (int ct = 0; ct < 16; ++ct) {
            short8 gf = *(const short8*)&gsf[buf][ct][lane][0];
            yacc[0][ct] = mfma16(pA[0], gf, yacc[0][ct]);
            yacc[1][ct] = mfma16(pA[1], gf, yacc[1][ct]);
        }
        lacc[0] = mfma16(pA[0], ones, lacc[0]);
        lacc[1] = mfma16(pA[1], ones, lacc[1]);
        __builtin_amdgcn_s_setprio(0);
    }

    if (valid) {
        u16* ypz = (z == 0) ? yp0 : yp1;
        u16* yb = ypz + (long)b * N_ * CI_;
#pragma unroll
        for (int h = 0; h < 2; ++h)
#pragma unroll
            for (int ct = 0; ct < 16; ++ct)
#pragma unroll
                for (int r = 0; r < 4; ++r)
                    yb[(long)(n0w + h * 16 + q * 4 + r) * CI_ + ct * 16 + lx] =
                        f2b(yacc[h][ct][r]);
        if (lx == 0) {
#pragma unroll
            for (int h = 0; h < 2; ++h)
#pragma unroll
                for (int r = 0; r < 4; ++r)
                    lpart[(long)z * BN_ + (long)b * N_ + n0w + h * 16 + q * 4 + r] =
                        lacc[h][r];
        }
    }
}

// ---------------------------------------------------------------------------
// gemm_w (n-paired): wy[m][c] = sum_k y[m][k]*Wt[c][k] + wb[c], where
// y = (yp0+yp1)[m][k] / l[m] combined on the fly. Each block computes a
// 128x256 output: acc[4][8] (128 accumulators, AGPR side). Bsf 16 row
// groups (32 KB), Asf unchanged (16 KB) -> 48 KB LDS, launch (256,2).
// XCD-grouped flat grid 400: xcd=id&7, j=id>>3, xt=xcd+8*(j>>1),
// n0=(j&1)*256; xt>=196 -> early return.
// Also accumulates per-channel BN sums (stats) via shfl + atomics.
// ---------------------------------------------------------------------------
__global__ __launch_bounds__(256, 2) void gemm_w(
    const u16* __restrict__ yp0, const u16* __restrict__ yp1,
    const float* __restrict__ lpart,
    const u16* __restrict__ Bt,       // cww [512][256]
    const u16* __restrict__ bias,     // cwb [512]
    u16* __restrict__ wy,             // [BN][512]
    float* __restrict__ stats)
{
    __shared__ __attribute__((aligned(16))) u16 Asf[2][8][64][8];   // 16 KB
    __shared__ __attribute__((aligned(16))) u16 Bsf[2][16][64][8];  // 32 KB

    const int t = threadIdx.x;
    const int wave = t >> 6, lane = t & 63;
    const int q = lane >> 4, lx = lane & 15;
    // XCD-grouped decode
    const int id = blockIdx.x;
    const int xcd = id & 7;
    const int j2 = id >> 3;              // 0..49
    const int xt = xcd + 8 * (j2 >> 1);
    if (xt >= 196) return;
    const int m0 = xt * 128;
    const int n0 = (j2 & 1) * 256;

    float rl[2];
#pragma unroll
    for (int i = 0; i < 2; ++i) {
        int row = m0 + (wave * 2 + i) * 16 + lx;
        rl[i] = 1.0f / (lpart[row] + lpart[BN_ + row]);
    }

    floatx4 zero4 = {0.f, 0.f, 0.f, 0.f};
    floatx4 acc[4][8];
#pragma unroll
    for (int i = 0; i < 4; ++i)
#pragma unroll
        for (int j = 0; j < 8; ++j) acc[i][j] = zero4;

    short8 va[2][2];
    auto loadA = [&](int k0) {
#pragma unroll
        for (int i = 0; i < 2; ++i) {
            long off = (long)(m0 + (wave * 2 + i) * 16 + lx) * CI_ + k0 + q * 8;
            va[i][0] = *(const short8*)(yp0 + off);
            va[i][1] = *(const short8*)(yp1 + off);
        }
    };
    auto writeA = [&](int buf) {
#pragma unroll
        for (int i = 0; i < 2; ++i) {
            u16 pk[8] __attribute__((aligned(16)));
#pragma unroll
            for (int e = 0; e < 8; ++e) {
                float v = (b2f(((const u16*)&va[i][0])[e]) +
                           b2f(((const u16*)&va[i][1])[e])) * rl[i];
                pk[e] = f2b(v);
            }
            *(short8*)&Asf[buf][wave * 2 + i][lane][0] = *(const short8*)pk;
        }
    };
    auto stageB = [&](int buf, int k0) {
#pragma unroll
        for (int i = 0; i < 4; ++i) {
            int rg = wave * 4 + i;
            gload_lds16(Bt + (long)(n0 + rg * 16 + lx) * CI_ + k0 + q * 8,
                        &Bsf[buf][rg][0][0]);
        }
    };

    loadA(0); writeA(0); stageB(0, 0);
    const int rg0 = (wave >> 1) * 4, cg0 = (wave & 1) * 8;
    const int NS = CI_ / 32;   // 8
    for (int s = 0; s < NS; ++s) {
        const int buf = s & 1;
        __syncthreads();
        if (s + 1 < NS) { loadA((s + 1) * 32); stageB(buf ^ 1, (s + 1) * 32); }
        short8 af[4];
#pragma unroll
        for (int i = 0; i < 4; ++i)
            af[i] = *(const short8*)&Asf[buf][rg0 + i][lane][0];
#pragma unroll
        for (int j = 0; j < 8; ++j) {
            short8 bfr = *(const short8*)&Bsf[buf][cg0 + j][lane][0];
#pragma unroll
            for (int i = 0; i < 4; ++i)
                acc[i][j] = mfma16(af[i], bfr, acc[i][j]);
        }
        if (s + 1 < NS) writeA(buf ^ 1);
    }

    // epilogue: bias, wy write, fused BN channel partials
    const int wr = (wave >> 1) * 64, wc = (wave & 1) * 128;
#pragma unroll
    for (int j = 0; j < 8; ++j) {
        int col = n0 + wc + j * 16 + lx;
        float bv = b2f(bias[col]);
        float cs = 0.f, cq = 0.f;
#pragma unroll
        for (int i = 0; i < 4; ++i)
#pragma unroll
            for (int r = 0; r < 4; ++r) {
                int row = m0 + wr + i * 16 + q * 4 + r;
                float v = acc[i][j][r] + bv;
                wy[(long)row * C_ + col] = f2b(v);
                cs += v; cq += v * v;
            }
        cs += __shfl_xor(cs, 16); cs += __shfl_xor(cs, 32);
        cq += __shfl_xor(cq, 16); cq += __shfl_xor(cq, 32);
        if (q == 0) {
            atomicAdd(&stats[col], cs);
            atomicAdd(&stats[C_ + col], cq);
        }
    }
}

// ---------------------------------------------------------------------------
// out[b][c][n] = (wy[b][n][c]-mean)*rstd*gamma + beta + xT[b][n][c]
// BN affine + residual folded into the LOAD phase (per-thread sc/sh for the
// 4 fixed channel columns computed once) -> single float[64][65] tile;
// phase 2 is a pure transposed write. x only read for the 4KB dtype flag.
// ---------------------------------------------------------------------------
__global__ __launch_bounds__(256) void bn_apply(
    const u16* __restrict__ wy, const u16* __restrict__ xT,
    const void* __restrict__ xv,
    const u16* __restrict__ gamma, const u16* __restrict__ beta,
    const float* __restrict__ stats, void* __restrict__ outv)
{
    const int fl = block_flag(xv);
    __shared__ float tile[64][65];
    const int t = threadIdx.x;
    const int nb0 = blockIdx.x * 64;
    const int c0 = blockIdx.y * 64;
    const int b = blockIdx.z;
    const float inv = 1.0f / (float)BN_;

    // per-thread BN constants for the 4 fixed channel columns
    const int colb = (t & 15) * 4;
    float sc[4], sh[4];
#pragma unroll
    for (int k = 0; k < 4; ++k) {
        int c = c0 + colb + k;
        float mean = stats[c] * inv;
        float var = stats[C_ + c] * inv - mean * mean;
        float rstd = rsqrtf(var + 1e-5f);
        sc[k] = b2f(gamma[c]) * rstd;
        sh[k] = b2f(beta[c]) - mean * sc[k];
    }

#pragma unroll
    for (int j = 0; j < 4; ++j) {
        int row = (t >> 4) + 16 * j;
        long off = ((long)b * N_ + nb0 + row) * C_ + c0 + colb;
        u16 lv[4] __attribute__((aligned(8)));
        u16 lx4[4] __attribute__((aligned(8)));
        *(uint64_t*)lv = *(const uint64_t*)(wy + off);
        *(uint64_t*)lx4 = *(const uint64_t*)(xT + off);
#pragma unroll
        for (int k = 0; k < 4; ++k)
            tile[row][colb + k] = b2f(lv[k]) * sc[k] + sh[k] + b2f(lx4[k]);
    }
    __syncthreads();
#pragma unroll
    for (int it = 0; it < 8; ++it) {
        int oc = (t >> 5) + 8 * it;
        int on = (t & 31) * 2;
        long base = ((long)b * C_ + c0 + oc) * N_ + nb0 + on;
        float v0 = tile[on][oc];
        float v1 = tile[on + 1][oc];
        if (fl) {
            ((u16*)outv)[base] = f2b(v0);
            ((u16*)outv)[base + 1] = f2b(v1);
        } else {
            ((float*)outv)[base] = v0;
            ((float*)outv)[base + 1] = v1;
        }
    }
}

// ---------------------------------------------------------------------------
extern "C" void kernel_launch(void* const* d_in, const int* in_sizes, int n_in,
                              void* d_out, int out_size, void* d_ws, size_t ws_size,
                              hipStream_t stream)
{
    (void)in_sizes; (void)n_in; (void)out_size; (void)ws_size;

    const size_t S = 12845056;               // one [B,N,CI] bf16 slab (bytes)
    const size_t SE = S / 2;                 // slab element count
    char* base = (char*)d_ws;
    u16*   xT    = (u16*)(base);             // [0, 2S)  convert->proj->bn_apply
    u16*   th    = (u16*)(base + 2 * S);     // [2S, 3S) proj->attn (ph=+SE)
    u16*   wy    = (u16*)(base + 2 * S);     // [2S, 4S) gemm_w->bn_apply
    u16*   gT    = (u16*)(base + 4 * S);     // [4S, 5S) proj->attn
    float* lpart = (float*)(base + 5 * S);                          // 200 KB
    float* stats = (float*)(base + 5 * S + (size_t)4 * BN_ * 4);
    u16*   cw    = (u16*)(base + 5 * S + (size_t)4 * BN_ * 4 + 4096);

    // canonical param offsets (convert_params segment order)
    u16* ctw = cw;
    u16* cww = cw + 393984;
    u16* cwb = cw + 525056;
    u16* cga = cw + 525568;
    u16* cbe = cw + 526080;

    u16* yp0 = (u16*)d_out;             // d_out = 2 slabs of scratch
    u16* yp1 = (u16*)d_out + SE;        // dead before bn_apply overwrites

    convert_params<<<dim3(64, 10), 256, 0, stream>>>(
        d_in[0], d_in[1], d_in[2], d_in[3], d_in[4], d_in[5], d_in[6],
        d_in[7], d_in[8], d_in[9], d_in[10], cw, stats);

    transpose_x<<<dim3(N_ / 64, C_ / 64, B_), 256, 0, stream>>>(d_in[0], xT);

    // fused theta/phi/g projections (XCD-grouped flat grid); g -> gT
    gemm_proj<<<dim3(1200, 1, 1), 256, 0, stream>>>(
        xT, ctw, th, gT, (long)SE);

    // XCD-grouped flat grid (decode inside kernel)
    attn<<<dim3(400, 1, 1), 256, 0, stream>>>(
        th, th + SE, gT, yp0, yp1, lpart);

    // W GEMM, n-paired (128x256 per block), XCD-grouped
    gemm_w<<<dim3(400, 1, 1), 256, 0, stream>>>(
        yp0, yp1, lpart, cww, cwb, wy, stats);

    bn_apply<<<dim3(N_ / 64, C_ / 64, B_), 256, 0, stream>>>(
        wy, xT, d_in[0], cga, cbe, stats, d_out);
}